// Round 7
// baseline (44.308 us; speedup 1.0000x reference)
//
#include <hip/hip_runtime.h>
#include <math.h>

#define N_S 1024
#define XD  768
#define LOW 300
#define KP  320     // f16 k-padding
#define KP2 160     // u32 (h2) per row

typedef _Float16 h2  __attribute__((ext_vector_type(2)));
typedef __fp16   g2  __attribute__((ext_vector_type(2)));
typedef _Float16 v8h __attribute__((ext_vector_type(8)));
typedef float    f4  __attribute__((ext_vector_type(4)));

union U32H2 { unsigned int u; h2 h; };
__device__ inline h2 u2h(unsigned int v){ U32H2 t; t.u = v; return t.h; }
__device__ inline unsigned int pk(float a, float b){
    g2 t = __builtin_amdgcn_cvt_pkrtz(a, b);
    return __builtin_bit_cast(unsigned int, t);
}
union U4V8 { uint4 u; v8h v; };

#define STR 34   // u32 row stride (64 f16 + 2-u32 pad)

// ---------------------------------------------------------------------------
// Kernel 1: projections via MFMA f16, f16 staged directly in LDS.
//   which==0 : hx[j][k] = sum_m x[j,m]*W1[m,k]
//   which==1 : hy[i][k] = sum_m y[i,m]*W1[768+m,k] + b1[k]
// (unchanged from round 6 — verified)
// ---------------------------------------------------------------------------
__global__ __launch_bounds__(512)
void gemm_h(const float* __restrict__ x, const float* __restrict__ y,
            const float* __restrict__ W1, const float* __restrict__ b1g,
            _Float16* __restrict__ hx_h, _Float16* __restrict__ hy_h)
{
    const int which = blockIdx.z;
    const float* A = which ? y : x;
    const float* W = W1 + (size_t)which * XD * LOW;
    _Float16* out = which ? hy_h : hx_h;

    const int n0 = blockIdx.x * 64;
    const int r0 = blockIdx.y * 64;

    __shared__ unsigned int As[2][64][STR];   // [row][k/2]
    __shared__ unsigned int Bs[2][64][STR];   // [ncol][k/2]

    const int tid = threadIdx.x;
    const int w = tid >> 6, l = tid & 63;
    const int wn = w >> 1, wm = w & 1;
    const int lr = l & 15, lg = l >> 4;

    const int arow = tid >> 3, aq = tid & 7;   // A staging: row, 8-m group
    const int bn = tid & 63, bms = tid >> 6;   // B staging: ncol, 8-m group
    const bool bin = (n0 + bn) < LOW;

    f4 acc[2] = {};

    float4 a0, a1; float bw[8];
    a0 = *(const float4*)&A[(size_t)(r0 + arow) * XD + aq * 8];
    a1 = *(const float4*)&A[(size_t)(r0 + arow) * XD + aq * 8 + 4];
    #pragma unroll
    for (int s = 0; s < 8; ++s)
        bw[s] = bin ? W[(size_t)(bms * 8 + s) * LOW + n0 + bn] : 0.f;

    const int NC = XD / 64;                    // 12
    for (int c = 0; c < NC; ++c) {
        const int buf = c & 1;
        {
            uint4 pa = { pk(a0.x,a0.y), pk(a0.z,a0.w), pk(a1.x,a1.y), pk(a1.z,a1.w) };
            *(uint4*)&As[buf][arow][aq * 4] = pa;
            uint4 pb = { pk(bw[0],bw[1]), pk(bw[2],bw[3]), pk(bw[4],bw[5]), pk(bw[6],bw[7]) };
            *(uint4*)&Bs[buf][bn][bms * 4] = pb;
        }
        __syncthreads();
        if (c + 1 < NC) {
            const int kb = (c + 1) * 64;
            a0 = *(const float4*)&A[(size_t)(r0 + arow) * XD + kb + aq * 8];
            a1 = *(const float4*)&A[(size_t)(r0 + arow) * XD + kb + aq * 8 + 4];
            #pragma unroll
            for (int s = 0; s < 8; ++s)
                bw[s] = bin ? W[(size_t)(kb + bms * 8 + s) * LOW + n0 + bn] : 0.f;
        }
        #pragma unroll
        for (int ks = 0; ks < 2; ++ks) {
            const int ko = ks * 16 + lg * 4;
            U4V8 bf; bf.u = *(const uint4*)&Bs[buf][wn * 16 + lr][ko];
            #pragma unroll
            for (int mt = 0; mt < 2; ++mt) {
                U4V8 af; af.u = *(const uint4*)&As[buf][wm * 32 + mt * 16 + lr][ko];
                acc[mt] = __builtin_amdgcn_mfma_f32_16x16x32_f16(af.v, bf.v, acc[mt], 0, 0, 0);
            }
        }
    }

    // D: col = l&15, row = 4*(l>>4)+r
    const int col = n0 + wn * 16 + lr;
    const float b1v = (which && col < LOW) ? b1g[col] : 0.f;
    #pragma unroll
    for (int mt = 0; mt < 2; ++mt)
        #pragma unroll
        for (int r = 0; r < 4; ++r) {
            const int row = r0 + wm * 32 + mt * 16 + lg * 4 + r;
            out[(size_t)row * KP + col] = (_Float16)(acc[mt][r] + b1v);
        }
}

// ---------------------------------------------------------------------------
// Kernel 2: pairwise critic, 4i x 4j register blocking, LDS-balanced.
//   s[i][j] = sum_k relu(hy[i,k]+hx[j,k]) * w2[k] + b2
//   part[i][jb] = sum_{j in block} e^{s[i][j]}       (exp(softplus)=1+e^s)
//   diag[i]     = softplus(s[i][i])
// 64x64 tile, 256 thr (1 block/CU), uint2 [kk2][row] LDS (b64 staging),
// w2 from uniform global loads (SGPR), double-buffered, 1 barrier/chunk.
// ---------------------------------------------------------------------------
#define NCH 10
__global__ __launch_bounds__(256)
void pair_kernel(const unsigned int* __restrict__ hx_h, const unsigned int* __restrict__ hy_h,
                 const float* __restrict__ W2, const float* __restrict__ b2,
                 float* __restrict__ part, float* __restrict__ diag)
{
    const int bx = blockIdx.x, by = blockIdx.y;
    const int j0 = bx * 64, i0 = by * 64;

    __shared__ uint2 Hy[2][8][68];   // [kk2][i], element = 2 k-pairs
    __shared__ uint2 Hx[2][8][68];   // [kk2][j]

    const int tid = threadIdx.x;
    const int tx = tid & 15;          // j = j0 + q*16 + tx
    const int ty = tid >> 4;          // i = i0 + ty*4 + r

    const int srow = tid >> 2, skq = tid & 3;   // staging: row, uint4 group

    const unsigned int* gy = &hy_h[(size_t)(i0 + srow) * KP2 + skq * 4];
    const unsigned int* gx = &hx_h[(size_t)(j0 + srow) * KP2 + skq * 4];

    uint4 ga = *(const uint4*)gy;
    uint4 gb = *(const uint4*)gx;

    float acc[4][4] = {};            // [r][q]
    const h2 hz = h2{(_Float16)0.f, (_Float16)0.f};

    for (int c = 0; c < NCH; ++c) {
        const int buf = c & 1;
        Hy[buf][skq*2  ][srow] = make_uint2(ga.x, ga.y);
        Hy[buf][skq*2+1][srow] = make_uint2(ga.z, ga.w);
        Hx[buf][skq*2  ][srow] = make_uint2(gb.x, gb.y);
        Hx[buf][skq*2+1][srow] = make_uint2(gb.z, gb.w);
        __syncthreads();
        if (c + 1 < NCH) {
            ga = *(const uint4*)(gy + (c + 1) * 16);
            gb = *(const uint4*)(gx + (c + 1) * 16);
        }

        // w2 chunk: k = c*32 .. c*32+31, uniform loads (SGPR), exact f4 tail
        unsigned int wp[16];
        {
            const int kb = c * 32;
            #pragma unroll
            for (int t = 0; t < 8; ++t) {
                float4 wv;
                if (kb + t * 4 + 3 < LOW) wv = *(const float4*)&W2[kb + t * 4];
                else wv = float4{0.f, 0.f, 0.f, 0.f};
                wp[t * 2]     = pk(wv.x, wv.y);
                wp[t * 2 + 1] = pk(wv.z, wv.w);
            }
        }

        #pragma unroll
        for (int kk2 = 0; kk2 < 8; ++kk2) {
            uint2 ya[4], xb[4];
            #pragma unroll
            for (int r = 0; r < 4; ++r) ya[r] = Hy[buf][kk2][ty * 4 + r];
            #pragma unroll
            for (int q = 0; q < 4; ++q) xb[q] = Hx[buf][kk2][q * 16 + tx];
            const h2 w0 = u2h(wp[kk2 * 2]);
            const h2 w1 = u2h(wp[kk2 * 2 + 1]);
            #pragma unroll
            for (int r = 0; r < 4; ++r) {
                const h2 a0 = u2h(ya[r].x);
                const h2 a1 = u2h(ya[r].y);
                #pragma unroll
                for (int q = 0; q < 4; ++q) {
                    const h2 b0 = u2h(xb[q].x);
                    const h2 b1 = u2h(xb[q].y);
                    h2 z0 = __builtin_elementwise_max(a0 + b0, hz);
                    h2 z1 = __builtin_elementwise_max(a1 + b1, hz);
                    acc[r][q] = __builtin_amdgcn_fdot2(z0, w0, acc[r][q], false);
                    acc[r][q] = __builtin_amdgcn_fdot2(z1, w1, acc[r][q], false);
                }
            }
        }
    }

    const float b2v = b2[0];
    #pragma unroll
    for (int r = 0; r < 4; ++r) {
        const int row = i0 + ty * 4 + r;
        float es = 0.f;
        #pragma unroll
        for (int q = 0; q < 4; ++q) {
            const float s = acc[r][q] + b2v;
            es += __expf(s);
            const int col = j0 + q * 16 + tx;
            if (col == row)
                diag[row] = fmaxf(s, 0.f) + __logf(1.f + __expf(-fabsf(s)));
        }
        #pragma unroll
        for (int o = 1; o <= 8; o <<= 1) es += __shfl_xor(es, o, 64);
        if (tx == 0) part[(size_t)row * 16 + bx] = es;
    }
}

// ---------------------------------------------------------------------------
// Kernel 3: per-row lse from 16 partials + final mean. One 1024-thr block.
//   lse_i = log(N + sum_jb part[i][jb]);  out = mean(diag - lse) - log N
// ---------------------------------------------------------------------------
__global__ __launch_bounds__(1024)
void lse_final(const float* __restrict__ part, const float* __restrict__ diag,
               float* __restrict__ out)
{
    const int i = threadIdx.x;
    const float4* p = (const float4*)(part + (size_t)i * 16);
    float s = 0.f;
    #pragma unroll
    for (int q = 0; q < 4; ++q) {
        float4 v = p[q];
        s += (v.x + v.y) + (v.z + v.w);
    }
    float c = diag[i] - __logf((float)N_S + s);

    #pragma unroll
    for (int o = 32; o > 0; o >>= 1) c += __shfl_xor(c, o, 64);
    __shared__ float ss[16];
    const int wid = i >> 6, lane = i & 63;
    if (lane == 0) ss[wid] = c;
    __syncthreads();
    if (i == 0) {
        float t = 0.f;
        #pragma unroll
        for (int q = 0; q < 16; ++q) t += ss[q];
        out[0] = t * (1.0f / N_S) - logf((float)N_S);
    }
}

// ---------------------------------------------------------------------------
extern "C" void kernel_launch(void* const* d_in, const int* in_sizes, int n_in,
                              void* d_out, int out_size, void* d_ws, size_t ws_size,
                              hipStream_t stream)
{
    const float* x  = (const float*)d_in[0];
    const float* y  = (const float*)d_in[1];
    const float* W1 = (const float*)d_in[2];
    const float* b1 = (const float*)d_in[3];
    const float* W2 = (const float*)d_in[4];
    const float* b2 = (const float*)d_in[5];
    float* out = (float*)d_out;

    unsigned int* hx_h = (unsigned int*)d_ws;             // N_S*KP2 u32
    unsigned int* hy_h = hx_h + (size_t)N_S * KP2;        // N_S*KP2 u32
    float* part = (float*)(hy_h + (size_t)N_S * KP2);     // N_S*16 f32
    float* diag = part + (size_t)N_S * 16;                // N_S f32

    dim3 g1(5, 16, 2);                    // ktiles(320/64), rowtiles, {x,y}
    gemm_h<<<g1, 512, 0, stream>>>(x, y, W1, b1,
                                   (_Float16*)hx_h, (_Float16*)hy_h);

    dim3 g2(16, 16);                      // j-tiles, i-tiles
    pair_kernel<<<g2, 256, 0, stream>>>(hx_h, hy_h, W2, b2, part, diag);

    lse_final<<<1, 1024, 0, stream>>>(part, diag, out);
}